// Round 1
// baseline (3276.676 us; speedup 1.0000x reference)
//
#include <hip/hip_runtime.h>
#include <math.h>

#define SEQ 2048
#define BATCH 64
#define INF 256
#define HID 256
#define NL 2

// ---------------------------------------------------------------------------
// Phase A: pre[l][m][h] = sum_i x[m][i] * W[l][h][i] + bias[l][h]
//   m = t*BATCH + b  (x is [SEQ,BATCH,IN] row-major = [M=131072][256])
//   W is [L][HID][IN] row-major (so both operands are row-major over k=i).
// l=0 tile -> pre0 (workspace), l=1 tile -> pre1 (aliased with d_out).
// 64x64 output tile per 256-thread block, 4x4 per thread, K staged in LDS
// transposed as [k][m] (pad 68 -> aligned float4 reads, conflict-light).
// ---------------------------------------------------------------------------
__global__ __launch_bounds__(256) void xw_kernel(
    const float* __restrict__ x,
    const float* __restrict__ W,
    const float* __restrict__ bias,
    float* __restrict__ pre0,
    float* __restrict__ pre1)
{
    __shared__ float As[64][68];
    __shared__ float Bs[64][68];

    const int mb = blockIdx.x * 64;          // row tile base (t*B+b)
    const int nb = blockIdx.y * 64;          // lh tile base in [0, 512)
    const int l  = nb >> 8;
    const int hb = nb & 255;

    const int tid = threadIdx.x;
    const int tx = tid & 15;                 // n sub (4 cols)
    const int ty = tid >> 4;                 // m sub (4 rows)

    const float* Wl = W + (size_t)l * HID * INF;

    float acc[4][4] = {};

    const int lrow = tid >> 4;               // 0..15 (staging row)
    const int lkq  = tid & 15;               // 0..15 -> k = lkq*4

    for (int kb = 0; kb < INF; kb += 64) {
        #pragma unroll
        for (int rr = 0; rr < 4; ++rr) {
            const int m = lrow + rr * 16;    // 0..63
            float4 va = *(const float4*)&x[(size_t)(mb + m) * INF + kb + lkq * 4];
            As[lkq*4 + 0][m] = va.x; As[lkq*4 + 1][m] = va.y;
            As[lkq*4 + 2][m] = va.z; As[lkq*4 + 3][m] = va.w;
            float4 vb = *(const float4*)&Wl[(size_t)(hb + m) * INF + kb + lkq * 4];
            Bs[lkq*4 + 0][m] = vb.x; Bs[lkq*4 + 1][m] = vb.y;
            Bs[lkq*4 + 2][m] = vb.z; Bs[lkq*4 + 3][m] = vb.w;
        }
        __syncthreads();

        #pragma unroll 8
        for (int k = 0; k < 64; ++k) {
            float4 a = *(const float4*)&As[k][ty * 4];
            float4 b = *(const float4*)&Bs[k][tx * 4];
            acc[0][0] = fmaf(a.x, b.x, acc[0][0]);
            acc[0][1] = fmaf(a.x, b.y, acc[0][1]);
            acc[0][2] = fmaf(a.x, b.z, acc[0][2]);
            acc[0][3] = fmaf(a.x, b.w, acc[0][3]);
            acc[1][0] = fmaf(a.y, b.x, acc[1][0]);
            acc[1][1] = fmaf(a.y, b.y, acc[1][1]);
            acc[1][2] = fmaf(a.y, b.z, acc[1][2]);
            acc[1][3] = fmaf(a.y, b.w, acc[1][3]);
            acc[2][0] = fmaf(a.z, b.x, acc[2][0]);
            acc[2][1] = fmaf(a.z, b.y, acc[2][1]);
            acc[2][2] = fmaf(a.z, b.z, acc[2][2]);
            acc[2][3] = fmaf(a.z, b.w, acc[2][3]);
            acc[3][0] = fmaf(a.w, b.x, acc[3][0]);
            acc[3][1] = fmaf(a.w, b.y, acc[3][1]);
            acc[3][2] = fmaf(a.w, b.z, acc[3][2]);
            acc[3][3] = fmaf(a.w, b.w, acc[3][3]);
        }
        __syncthreads();
    }

    float bv[4];
    #pragma unroll
    for (int j = 0; j < 4; ++j)
        bv[j] = bias[l * HID + hb + tx * 4 + j];

    float* dst = (l == 0) ? pre0 : pre1;
    #pragma unroll
    for (int i = 0; i < 4; ++i) {
        float4 o;
        o.x = acc[i][0] + bv[0];
        o.y = acc[i][1] + bv[1];
        o.z = acc[i][2] + bv[2];
        o.w = acc[i][3] + bv[3];
        *(float4*)&dst[(size_t)(mb + ty * 4 + i) * HID + hb + tx * 4] = o;
    }
}

// ---------------------------------------------------------------------------
// Phase B: 128 independent recurrences, one block per (layer, batch).
// Block = 1024 threads: g = tid&255 (output row of U), c = tid>>8 (k-chunk).
// Each thread pins U[l][g][c*64 .. c*64+63] in 64 VGPRs. h lives in LDS.
// Per step: 64 reg-FMAs -> 4-way LDS reduce -> tanh -> write h (+ output).
// pre[t+1] load is issued by the reducer threads at the end of step t so its
// HBM latency hides under the next FMA phase.
// NOTE: pre1 and out alias (same buffer) -> no __restrict__ here.
// ---------------------------------------------------------------------------
__global__ __launch_bounds__(1024) void rnn_kernel(
    const float* __restrict__ h0,
    const float* __restrict__ U,
    const float* pre0,
    const float* pre1,
    float* out,
    float* hn)
{
    __shared__ float h_lds[HID];
    __shared__ float part[4 * HID];

    const int l = blockIdx.x >> 6;
    const int b = blockIdx.x & 63;
    const int tid = threadIdx.x;
    const int g = tid & 255;
    const int c = tid >> 8;

    float u[64];
    const float* Urow = U + (size_t)l * HID * HID + (size_t)g * HID + c * 64;
    #pragma unroll
    for (int q = 0; q < 16; ++q)
        *(float4*)&u[q * 4] = *(const float4*)&Urow[q * 4];

    if (tid < HID)
        h_lds[tid] = h0[(size_t)l * BATCH * HID + (size_t)b * HID + tid];
    __syncthreads();

    const float* pre = (l == 0) ? pre0 : pre1;

    float preCur = 0.0f;
    if (tid < HID)
        preCur = pre[(size_t)b * HID + tid];   // t = 0

    for (int t = 0; t < SEQ; ++t) {
        float a0 = 0.f, a1 = 0.f, a2 = 0.f, a3 = 0.f;
        #pragma unroll
        for (int q = 0; q < 16; ++q) {
            float4 hv = *(const float4*)&h_lds[c * 64 + q * 4];
            a0 = fmaf(u[q * 4 + 0], hv.x, a0);
            a1 = fmaf(u[q * 4 + 1], hv.y, a1);
            a2 = fmaf(u[q * 4 + 2], hv.z, a2);
            a3 = fmaf(u[q * 4 + 3], hv.w, a3);
        }
        part[c * HID + g] = (a0 + a1) + (a2 + a3);
        __syncthreads();

        if (tid < HID) {
            float s = part[tid] + part[HID + tid] + part[2 * HID + tid]
                    + part[3 * HID + tid];
            float v = tanhf(s + preCur);
            h_lds[tid] = v;
            if (l == 1)
                out[(size_t)t * BATCH * HID + (size_t)b * HID + tid] = v;
            if (t + 1 < SEQ)
                preCur = pre[(size_t)(t + 1) * BATCH * HID + (size_t)b * HID + tid];
        }
        __syncthreads();
    }

    if (tid < HID)
        hn[(size_t)l * BATCH * HID + (size_t)b * HID + tid] = h_lds[tid];
}

extern "C" void kernel_launch(void* const* d_in, const int* in_sizes, int n_in,
                              void* d_out, int out_size, void* d_ws, size_t ws_size,
                              hipStream_t stream) {
    const float* x  = (const float*)d_in[0];   // [SEQ][B][IN]
    const float* h0 = (const float*)d_in[1];   // [L][B][H]
    const float* W  = (const float*)d_in[2];   // [L][H][IN]
    const float* U  = (const float*)d_in[3];   // [L][H][H]
    const float* bs = (const float*)d_in[4];   // [L][H]

    float* out  = (float*)d_out;                       // [SEQ][B][H] then [L][B][H]
    float* pre0 = (float*)d_ws;                        // l=0 preacts, 134 MB
    float* pre1 = out;                                 // l=1 preacts staged in-place
    float* hn   = out + (size_t)SEQ * BATCH * HID;

    dim3 gridA(SEQ * BATCH / 64, (NL * HID) / 64);
    xw_kernel<<<gridA, 256, 0, stream>>>(x, W, bs, pre0, pre1);

    rnn_kernel<<<NL * BATCH, 1024, 0, stream>>>(h0, U, pre0, pre1, out, hn);
}

// Round 3
// 2212.255 us; speedup vs baseline: 1.4811x; 1.4811x over previous
//
#include <hip/hip_runtime.h>
#include <math.h>

#define SEQ 2048
#define BATCH 64
#define INF 256
#define HID 256
#define NL 2

// ---------------------------------------------------------------------------
// Phase A: pre[l][m][h] = sum_i x[m][i] * W[l][h][i] + bias[l][h]
// (unchanged from round 1 — ~600 us, optimize after rnn_kernel is fixed)
// ---------------------------------------------------------------------------
__global__ __launch_bounds__(256) void xw_kernel(
    const float* __restrict__ x,
    const float* __restrict__ W,
    const float* __restrict__ bias,
    float* __restrict__ pre0,
    float* __restrict__ pre1)
{
    __shared__ float As[64][68];
    __shared__ float Bs[64][68];

    const int mb = blockIdx.x * 64;
    const int nb = blockIdx.y * 64;
    const int l  = nb >> 8;
    const int hb = nb & 255;

    const int tid = threadIdx.x;
    const int tx = tid & 15;
    const int ty = tid >> 4;

    const float* Wl = W + (size_t)l * HID * INF;

    float acc[4][4] = {};

    const int lrow = tid >> 4;
    const int lkq  = tid & 15;

    for (int kb = 0; kb < INF; kb += 64) {
        #pragma unroll
        for (int rr = 0; rr < 4; ++rr) {
            const int m = lrow + rr * 16;
            float4 va = *(const float4*)&x[(size_t)(mb + m) * INF + kb + lkq * 4];
            As[lkq*4 + 0][m] = va.x; As[lkq*4 + 1][m] = va.y;
            As[lkq*4 + 2][m] = va.z; As[lkq*4 + 3][m] = va.w;
            float4 vb = *(const float4*)&Wl[(size_t)(hb + m) * INF + kb + lkq * 4];
            Bs[lkq*4 + 0][m] = vb.x; Bs[lkq*4 + 1][m] = vb.y;
            Bs[lkq*4 + 2][m] = vb.z; Bs[lkq*4 + 3][m] = vb.w;
        }
        __syncthreads();

        #pragma unroll 8
        for (int k = 0; k < 64; ++k) {
            float4 a = *(const float4*)&As[k][ty * 4];
            float4 b = *(const float4*)&Bs[k][tx * 4];
            acc[0][0] = fmaf(a.x, b.x, acc[0][0]);
            acc[0][1] = fmaf(a.x, b.y, acc[0][1]);
            acc[0][2] = fmaf(a.x, b.z, acc[0][2]);
            acc[0][3] = fmaf(a.x, b.w, acc[0][3]);
            acc[1][0] = fmaf(a.y, b.x, acc[1][0]);
            acc[1][1] = fmaf(a.y, b.y, acc[1][1]);
            acc[1][2] = fmaf(a.y, b.z, acc[1][2]);
            acc[1][3] = fmaf(a.y, b.w, acc[1][3]);
            acc[2][0] = fmaf(a.z, b.x, acc[2][0]);
            acc[2][1] = fmaf(a.z, b.y, acc[2][1]);
            acc[2][2] = fmaf(a.z, b.z, acc[2][2]);
            acc[2][3] = fmaf(a.z, b.w, acc[2][3]);
            acc[3][0] = fmaf(a.w, b.x, acc[3][0]);
            acc[3][1] = fmaf(a.w, b.y, acc[3][1]);
            acc[3][2] = fmaf(a.w, b.z, acc[3][2]);
            acc[3][3] = fmaf(a.w, b.w, acc[3][3]);
        }
        __syncthreads();
    }

    float bv[4];
    #pragma unroll
    for (int j = 0; j < 4; ++j)
        bv[j] = bias[l * HID + hb + tx * 4 + j];

    float* dst = (l == 0) ? pre0 : pre1;
    #pragma unroll
    for (int i = 0; i < 4; ++i) {
        float4 o;
        o.x = acc[i][0] + bv[0];
        o.y = acc[i][1] + bv[1];
        o.z = acc[i][2] + bv[2];
        o.w = acc[i][3] + bv[3];
        *(float4*)&dst[(size_t)(mb + ty * 4 + i) * HID + hb + tx * 4] = o;
    }
}

// fast tanh: clamp + hw exp. |err| ~1e-6 rel, fine vs 2e-2 threshold.
__device__ __forceinline__ float tanh_fast(float x) {
    float xc = fminf(fmaxf(x, -12.0f), 12.0f);
    float e  = __expf(2.0f * xc);            // v_exp_f32 path
    return __fdividef(e - 1.0f, e + 1.0f);   // v_rcp + mul
}

// ---------------------------------------------------------------------------
// Phase B v2: one block per (layer, batch) chain. 1024 threads.
//   g = tid>>2  (output row, 0..255),  c = tid&3 (k-chunk of 64).
// U row chunk pinned in 16 float4 VGPRs (launch_bounds(1024,4) -> 128-reg cap).
// Per step: 64 reg FMAs -> 2x shfl_xor butterfly (lanes 4c..4c+3 share g)
// -> tanh -> write h ping-pong buffer -> ONE barrier.
// LDS h layout: [2 bufs][4 segs][72] — stride 72 floats = 288 B (16B aligned,
// segs land on distinct bank quartets -> conflict-free ds_read_b128).
// ---------------------------------------------------------------------------
__global__ __launch_bounds__(1024, 4) void rnn_kernel(
    const float* __restrict__ h0,
    const float* __restrict__ U,
    const float* pre0,
    const float* pre1,
    float* out,
    float* hn)
{
    __shared__ float h_lds[2][4][72];

    const int l = blockIdx.x >> 6;
    const int b = blockIdx.x & 63;
    const int tid = threadIdx.x;
    const int g = tid >> 2;           // 0..255
    const int c = tid & 3;            // 0..3

    // pin U[l][g][c*64 .. c*64+63] in registers
    float4 u4[16];
    const float* Urow = U + (size_t)l * HID * HID + (size_t)g * HID + c * 64;
    #pragma unroll
    for (int q = 0; q < 16; ++q)
        u4[q] = *(const float4*)&Urow[q * 4];

    if (tid < HID)
        h_lds[0][tid >> 6][tid & 63] = h0[(size_t)l * BATCH * HID + (size_t)b * HID + tid];
    __syncthreads();

    const float* pre = (l == 0) ? pre0 : pre1;
    const size_t bh = (size_t)b * HID + g;

    float preCur = pre[bh];           // t = 0 (redundant across 4 lanes, cached)
    float v = 0.0f;
    int cur = 0;

    for (int t = 0; t < SEQ; ++t) {
        // prefetch next pre early so HBM latency hides under the FMAs
        float preNext = (t + 1 < SEQ) ? pre[(size_t)(t + 1) * BATCH * HID + bh] : 0.0f;

        float a0 = 0.f, a1 = 0.f, a2 = 0.f, a3 = 0.f;
        const float* hseg = &h_lds[cur][c][0];
        #pragma unroll
        for (int q = 0; q < 16; ++q) {
            float4 hv = *(const float4*)&hseg[q * 4];
            a0 = fmaf(u4[q].x, hv.x, a0);
            a1 = fmaf(u4[q].y, hv.y, a1);
            a2 = fmaf(u4[q].z, hv.z, a2);
            a3 = fmaf(u4[q].w, hv.w, a3);
        }
        float s = (a0 + a1) + (a2 + a3);
        s += __shfl_xor(s, 1);
        s += __shfl_xor(s, 2);        // all 4 lanes now hold the full dot

        v = tanh_fast(s + preCur);

        if (c == 0) {
            h_lds[cur ^ 1][g >> 6][g & 63] = v;
            if (l == 1)
                out[(size_t)t * BATCH * HID + bh] = v;
        }
        preCur = preNext;
        cur ^= 1;
        __syncthreads();
    }

    if (c == 0)
        hn[(size_t)l * BATCH * HID + bh] = v;
}

extern "C" void kernel_launch(void* const* d_in, const int* in_sizes, int n_in,
                              void* d_out, int out_size, void* d_ws, size_t ws_size,
                              hipStream_t stream) {
    const float* x  = (const float*)d_in[0];   // [SEQ][B][IN]
    const float* h0 = (const float*)d_in[1];   // [L][B][H]
    const float* W  = (const float*)d_in[2];   // [L][H][IN]
    const float* U  = (const float*)d_in[3];   // [L][H][H]
    const float* bs = (const float*)d_in[4];   // [L][H]

    float* out  = (float*)d_out;               // [SEQ][B][H] then [L][B][H]
    float* pre0 = (float*)d_ws;                // l=0 preacts (134 MB)
    float* pre1 = out;                         // l=1 preacts staged in-place
    float* hn   = out + (size_t)SEQ * BATCH * HID;

    dim3 gridA(SEQ * BATCH / 64, (NL * HID) / 64);
    xw_kernel<<<gridA, 256, 0, stream>>>(x, W, bs, pre0, pre1);

    rnn_kernel<<<NL * BATCH, 1024, 0, stream>>>(h0, U, pre0, pre1, out, hn);
}